// Round 3
// baseline (322.258 us; speedup 1.0000x reference)
//
#include <hip/hip_runtime.h>
#include <hip/hip_bf16.h>

// ---------------------------------------------------------------------------
// RRN forward, MI355X.
//   k0: transpose all tail weight matrices (coalesced access in k4)
//   k1: A32/B32 projections (fp32) + Wf2 -> f16 hi + f16 lo split
//   k2: pairwise MLP core (f16 MFMA hi/lo, h rounded once from fp32)
//       grid 512 blocks -> 2 blocks/CU -> 4 waves/SIMD
//   k4: fused k3+tail: SM = Wf3 @ S -> g_mlp -> LSTM -> o MLP
//       all weight loads coalesced via transposed layouts
// ---------------------------------------------------------------------------

#define NN   512
#define HH   128
#define F1D  256
#define F2D  256
#define MSGD 128
#define OUTD 64
#define ICHUNK 32

typedef _Float16 half_t;
typedef _Float16 half8 __attribute__((ext_vector_type(8)));
typedef float float2_t __attribute__((ext_vector_type(2)));
typedef float float4_t __attribute__((ext_vector_type(4)));
typedef float float8_t __attribute__((ext_vector_type(8)));

__device__ __forceinline__ float sigmoidf_(float x) {
    return 1.0f / (1.0f + __expf(-x));
}

// ---- workspace layout (float offsets) ----
#define WS_A32    0          // 512*256
#define WS_B32    131072     // 512*256
#define WS_WHI_B  1048576    // byte offset, 128KB (f16)
#define WS_WLO_B  1179648    // byte offset, 128KB (f16)
#define WS_S      327680     // float off 1310720B/4: 512*256
#define WS_WTG1   458752     // [256][256]
#define WS_WTG2   524288     // [256][256]
#define WS_WTG3   589824     // [256][128]
#define WS_WTIH   622592     // [128][512]
#define WS_WTHH   688128     // [128][512]
#define WS_WTO1   753664     // [128][256]
#define WS_WTO2   786432     // [256][64]
#define WS_WT3    802816     // [256][128]

// ---------------- k0: tiled transpose of 8 weight matrices ----------------
// 92 blocks x 256 threads; 64x64 tiles.
__constant__ int c_rows[8] = {256, 256, 128, 512, 512, 256,  64, 128};
__constant__ int c_cols[8] = {256, 256, 256, 128, 128, 128, 256, 256};
__constant__ int c_cum[8]  = { 16,  32,  40,  56,  72,  80,  84,  92};
__constant__ int c_dst[8]  = {WS_WTG1, WS_WTG2, WS_WTG3, WS_WTIH,
                              WS_WTHH, WS_WTO1, WS_WTO2, WS_WT3};

__global__ void k0_transpose(const float* __restrict__ s0, const float* __restrict__ s1,
                             const float* __restrict__ s2, const float* __restrict__ s3,
                             const float* __restrict__ s4, const float* __restrict__ s5,
                             const float* __restrict__ s6, const float* __restrict__ s7,
                             float* __restrict__ ws) {
    __shared__ float tile[64][65];
    const int t = threadIdx.x;
    int bid = blockIdx.x;

    int m = 0;
    while (m < 7 && bid >= c_cum[m]) ++m;
    const int base = (m == 0) ? 0 : c_cum[m - 1];
    const int local = bid - base;
    const int R = c_rows[m], C = c_cols[m];
    const int tcols = C >> 6;
    const int tr = local / tcols, tc = local % tcols;

    const float* src;
    switch (m) {
        case 0: src = s0; break; case 1: src = s1; break;
        case 2: src = s2; break; case 3: src = s3; break;
        case 4: src = s4; break; case 5: src = s5; break;
        case 6: src = s6; break; default: src = s7; break;
    }
    float* dst = ws + c_dst[m];

#pragma unroll
    for (int q = 0; q < 16; ++q) {
        int idx = q * 256 + t;
        int ly = idx >> 6, lx = idx & 63;
        tile[ly][lx] = src[(tr * 64 + ly) * C + tc * 64 + lx];
    }
    __syncthreads();
#pragma unroll
    for (int q = 0; q < 16; ++q) {
        int idx = q * 256 + t;
        int ly = idx >> 6, lx = idx & 63;
        dst[(tc * 64 + ly) * R + tr * 64 + lx] = tile[lx][ly];
    }
}

// ---------------- k1: projections (fp32 out) + Wf2 hi/lo split ----------------
__global__ void k1_proj(const float* __restrict__ hidden,
                        const float* __restrict__ Wf1,
                        const float* __restrict__ bf1,
                        const float* __restrict__ Wf2,
                        float* __restrict__ A32,
                        float* __restrict__ B32,
                        half_t* __restrict__ Whi,
                        half_t* __restrict__ Wlo) {
    __shared__ float hid[4][HH];
    const int t = threadIdx.x;
    const int i0 = blockIdx.x * 4;
    for (int q = t; q < 4 * HH; q += 256)
        hid[q >> 7][q & 127] = hidden[(i0 + (q >> 7)) * HH + (q & 127)];
    __syncthreads();

    float accA[4], accB[4];
    const float b = bf1[t];
#pragma unroll
    for (int r = 0; r < 4; ++r) { accA[r] = b; accB[r] = 0.0f; }

    const float* wr = Wf1 + t * 256;
#pragma unroll 4
    for (int k = 0; k < HH; k += 4) {
        float4_t wa = *(const float4_t*)(wr + k);
        float4_t wb = *(const float4_t*)(wr + HH + k);
#pragma unroll
        for (int r = 0; r < 4; ++r) {
            const float* hp = &hid[r][k];
            accA[r] += wa[0]*hp[0] + wa[1]*hp[1] + wa[2]*hp[2] + wa[3]*hp[3];
            accB[r] += wb[0]*hp[0] + wb[1]*hp[1] + wb[2]*hp[2] + wb[3]*hp[3];
        }
    }
#pragma unroll
    for (int r = 0; r < 4; ++r) {
        A32[(i0 + r) * F1D + t] = accA[r];
        B32[(i0 + r) * F1D + t] = accB[r];
    }
    for (int q = t; q < 512; q += 256) {
        int idx = blockIdx.x * 512 + q;
        float wv = Wf2[idx];
        half_t hi = (half_t)wv;
        Whi[idx] = hi;
        Wlo[idx] = (half_t)((wv - (float)hi) * 4096.0f);
    }
}

// ---------------- k2: pairwise MLP core ----------------
// grid (16 i-chunks, 32 j-tiles) x 512 threads (8 waves), 2 blocks/CU.
__global__ __launch_bounds__(512, 2)
void k2_pairwise(const float* __restrict__ A32,
                 const float* __restrict__ B32,
                 const half_t* __restrict__ Whi,
                 const half_t* __restrict__ Wlo,
                 const float* __restrict__ bf2,
                 float* __restrict__ S) {
    __shared__ float Alds[ICHUNK * F1D];   // 32 KB

    const int tid = threadIdx.x;
    const int lane = tid & 63;
    const int w = tid >> 6;           // wave 0..7
    const int l15 = lane & 15;
    const int g4 = lane >> 4;         // 0..3
    const int j0 = blockIdx.y * 16;
    const int i0 = blockIdx.x * ICHUNK;

    // stage A rows for this i-chunk
    {
        const float4_t* src = (const float4_t*)(A32 + (size_t)i0 * F1D);
        float4_t* dst = (float4_t*)Alds;
        for (int q = tid; q < ICHUNK * F1D / 4; q += 512) dst[q] = src[q];
    }

    // persistent W fragments: n = w*32 + nt*16 + l15, k = ks*32 + g4*8 + e
    half8 Wh[2][8], Wl[2][8];
#pragma unroll
    for (int nt = 0; nt < 2; ++nt)
#pragma unroll
        for (int ks = 0; ks < 8; ++ks) {
            const size_t off = (size_t)(w*32 + nt*16 + l15) * F1D + ks*32 + g4*8;
            Wh[nt][ks] = *(const half8*)(Whi + off);
            Wl[nt][ks] = *(const half8*)(Wlo + off);
        }

    // persistent B' fragments (fp32) for this block's 16 j's
    float8_t Bk[8];
#pragma unroll
    for (int ks = 0; ks < 8; ++ks)
        Bk[ks] = *(const float8_t*)(B32 + (size_t)(j0 + l15) * F1D + ks*32 + g4*8);

    float b2v[2];
#pragma unroll
    for (int nt = 0; nt < 2; ++nt) b2v[nt] = bf2[w*32 + nt*16 + l15];

    float4_t acc[2];
#pragma unroll
    for (int nt = 0; nt < 2; ++nt)
#pragma unroll
        for (int r = 0; r < 4; ++r) acc[nt][r] = 0.0f;

    __syncthreads();

    for (int io = 0; io < ICHUNK; ++io) {
        const float* Ar = Alds + io * F1D;

        float4_t C[2], Cl[2];
#pragma unroll
        for (int nt = 0; nt < 2; ++nt)
#pragma unroll
            for (int r = 0; r < 4; ++r) { C[nt][r] = 0.0f; Cl[nt][r] = 0.0f; }

#pragma unroll
        for (int ks = 0; ks < 8; ++ks) {
            float8_t a = *(const float8_t*)(Ar + ks*32 + g4*8);
            float8_t s = a + Bk[ks];
            half8 hf;
#pragma unroll
            for (int e = 0; e < 8; ++e) {
                float v = fmaxf(s[e], 0.0f);   // relu in fp32
                hf[e] = (half_t)v;             // single RTN rounding
            }
            C[0]  = __builtin_amdgcn_mfma_f32_16x16x32_f16(hf, Wh[0][ks], C[0], 0, 0, 0);
            C[1]  = __builtin_amdgcn_mfma_f32_16x16x32_f16(hf, Wh[1][ks], C[1], 0, 0, 0);
            Cl[0] = __builtin_amdgcn_mfma_f32_16x16x32_f16(hf, Wl[0][ks], Cl[0], 0, 0, 0);
            Cl[1] = __builtin_amdgcn_mfma_f32_16x16x32_f16(hf, Wl[1][ks], Cl[1], 0, 0, 0);
        }
#pragma unroll
        for (int nt = 0; nt < 2; ++nt) {
#pragma unroll
            for (int r = 0; r < 4; ++r) {
                float v = fmaf(Cl[nt][r], 2.44140625e-4f, C[nt][r]) + b2v[nt];
                acc[nt][r] += fmaxf(v, 0.0f);
            }
        }
    }

    // C layout: col = l15 (n), row = g4*4 + r (jj)
#pragma unroll
    for (int nt = 0; nt < 2; ++nt)
#pragma unroll
        for (int r = 0; r < 4; ++r)
            atomicAdd(&S[(size_t)(j0 + g4*4 + r) * F2D + w*32 + nt*16 + l15], acc[nt][r]);
}

// ---------------- k4: fused message-apply + g_mlp + LSTM + o MLP ----------------
// 128 blocks x 256 threads (4 waves); wave w owns row blockIdx.x*4 + w.
// All weight reads coalesced via transposed layouts; acts via LDS broadcast.
__global__ __launch_bounds__(256)
void k4_tail(const float* __restrict__ x,
             const float* __restrict__ h0,
             const float* __restrict__ c0,
             const float* __restrict__ S,
             const float* __restrict__ ws,
             const float* __restrict__ bf3,
             const float* __restrict__ bg1, const float* __restrict__ bg2,
             const float* __restrict__ bg3,
             const float* __restrict__ b_ih, const float* __restrict__ b_hh,
             const float* __restrict__ bo1, const float* __restrict__ bo2,
             float* __restrict__ out,
             float* __restrict__ hid_out,
             float* __restrict__ h_out,
             float* __restrict__ c_out) {
    __shared__ float Sl[4][256];
    __shared__ float gin[4][256];
    __shared__ float g1b[4][256];
    __shared__ float g2b[4][256];
    __shared__ float igb[4][128];
    __shared__ float gt[4][512];
    __shared__ float h0b[4][128], c0b[4][128], hb[4][128];
    __shared__ float o1b[4][256];

    const float* WT3  = ws + WS_WT3;
    const float* WTg1 = ws + WS_WTG1;
    const float* WTg2 = ws + WS_WTG2;
    const float* WTg3 = ws + WS_WTG3;
    const float* WTih = ws + WS_WTIH;
    const float* WThh = ws + WS_WTHH;
    const float* WTo1 = ws + WS_WTO1;
    const float* WTo2 = ws + WS_WTO2;

    const int t = threadIdx.x;
    const int w = t >> 6;        // wave = local row
    const int lane = t & 63;
    const int row = blockIdx.x * 4 + w;

    // stage this wave's row (coalesced within wave)
    {
        const float* xr = x + row * HH;
        const float* hr = h0 + row * HH;
        const float* cr = c0 + row * HH;
        gin[w][lane]      = xr[lane];
        gin[w][64 + lane] = xr[64 + lane];
        h0b[w][lane]      = hr[lane];
        h0b[w][64 + lane] = hr[64 + lane];
        c0b[w][lane]      = cr[lane];
        c0b[w][64 + lane] = cr[64 + lane];
        const float4_t* Sr = (const float4_t*)(S + (size_t)row * F2D);
        ((float4_t*)Sl[w])[lane] = Sr[lane];
    }
    // (no barrier needed: each wave consumes only its own row until LSTM)

    // SM = N*bf3 + Wf3 @ S[row]  -> gin[w][128..255]
    {
        const int m2 = lane * 2;
        float a0 = 512.0f * bf3[m2];
        float a1 = 512.0f * bf3[m2 + 1];
#pragma unroll 4
        for (int n = 0; n < 256; n += 4) {
            float4_t sv = *(const float4_t*)&Sl[w][n];
#pragma unroll
            for (int j = 0; j < 4; ++j) {
                float2_t wv = *(const float2_t*)&WT3[(n + j) * 128 + m2];
                a0 += sv[j] * wv[0];
                a1 += sv[j] * wv[1];
            }
        }
        gin[w][128 + m2]     = a0;
        gin[w][128 + m2 + 1] = a1;
    }

    // g1 = relu(gin @ Wg1.T + bg1)
    {
        const int n0 = lane * 4;
        float4_t a = *(const float4_t*)&bg1[n0];
#pragma unroll 4
        for (int k = 0; k < 256; k += 4) {
            float4_t av = *(const float4_t*)&gin[w][k];
#pragma unroll
            for (int j = 0; j < 4; ++j) {
                float4_t wv = *(const float4_t*)&WTg1[(k + j) * 256 + n0];
                a += av[j] * wv;
            }
        }
#pragma unroll
        for (int e = 0; e < 4; ++e) a[e] = fmaxf(a[e], 0.0f);
        *(float4_t*)&g1b[w][n0] = a;
    }

    // g2 = relu(g1 @ Wg2.T + bg2)
    {
        const int n0 = lane * 4;
        float4_t a = *(const float4_t*)&bg2[n0];
#pragma unroll 4
        for (int k = 0; k < 256; k += 4) {
            float4_t av = *(const float4_t*)&g1b[w][k];
#pragma unroll
            for (int j = 0; j < 4; ++j) {
                float4_t wv = *(const float4_t*)&WTg2[(k + j) * 256 + n0];
                a += av[j] * wv;
            }
        }
#pragma unroll
        for (int e = 0; e < 4; ++e) a[e] = fmaxf(a[e], 0.0f);
        *(float4_t*)&g2b[w][n0] = a;
    }

    // input_g = g2 @ Wg3.T + bg3
    {
        const int m2 = lane * 2;
        float a0 = bg3[m2], a1 = bg3[m2 + 1];
#pragma unroll 4
        for (int k = 0; k < 256; k += 4) {
            float4_t av = *(const float4_t*)&g2b[w][k];
#pragma unroll
            for (int j = 0; j < 4; ++j) {
                float2_t wv = *(const float2_t*)&WTg3[(k + j) * 128 + m2];
                a0 += av[j] * wv[0];
                a1 += av[j] * wv[1];
            }
        }
        igb[w][m2]     = a0;
        igb[w][m2 + 1] = a1;
    }

    // gates = input_g @ W_ih.T + b_ih + h0 @ W_hh.T + b_hh
#pragma unroll
    for (int hf = 0; hf < 2; ++hf) {
        const int n0 = lane * 4 + hf * 256;
        float4_t a = *(const float4_t*)&b_ih[n0];
        float4_t a2 = *(const float4_t*)&b_hh[n0];
        a += a2;
#pragma unroll 4
        for (int k = 0; k < 128; k += 4) {
            float4_t iv = *(const float4_t*)&igb[w][k];
            float4_t hv = *(const float4_t*)&h0b[w][k];
#pragma unroll
            for (int j = 0; j < 4; ++j) {
                float4_t wi = *(const float4_t*)&WTih[(k + j) * 512 + n0];
                float4_t wh = *(const float4_t*)&WThh[(k + j) * 512 + n0];
                a += iv[j] * wi + hv[j] * wh;
            }
        }
        *(float4_t*)&gt[w][n0] = a;
    }
    __syncthreads();

    // LSTM elementwise
    {
        const int n = t & 127;
        const int rb = (t >> 7) * 2;
#pragma unroll
        for (int rr = 0; rr < 2; ++rr) {
            const int r = rb + rr;
            const int grow = blockIdx.x * 4 + r;
            float ig_ = sigmoidf_(gt[r][n]);
            float fg  = sigmoidf_(gt[r][128 + n]);
            float gg  = tanhf(gt[r][256 + n]);
            float og  = sigmoidf_(gt[r][384 + n]);
            float c = fg * c0b[r][n] + ig_ * gg;
            float h = og * tanhf(c);
            hb[r][n] = h;
            hid_out[grow * HH + n] = h;
            h_out[grow * HH + n]   = h;
            c_out[grow * HH + n]   = c;
        }
    }
    __syncthreads();

    // o1 = relu(h @ Wo1.T + bo1)
    {
        const int n0 = lane * 4;
        float4_t a = *(const float4_t*)&bo1[n0];
#pragma unroll 4
        for (int k = 0; k < 128; k += 4) {
            float4_t av = *(const float4_t*)&hb[w][k];
#pragma unroll
            for (int j = 0; j < 4; ++j) {
                float4_t wv = *(const float4_t*)&WTo1[(k + j) * 256 + n0];
                a += av[j] * wv;
            }
        }
#pragma unroll
        for (int e = 0; e < 4; ++e) a[e] = fmaxf(a[e], 0.0f);
        *(float4_t*)&o1b[w][n0] = a;
    }

    // out = o1 @ Wo2.T + bo2
    {
        const int n = lane;   // 64 outputs
        float a = bo2[n];
#pragma unroll 4
        for (int k = 0; k < 256; k += 4) {
            float4_t av = *(const float4_t*)&o1b[w][k];
#pragma unroll
            for (int j = 0; j < 4; ++j)
                a += av[j] * WTo2[(k + j) * 64 + n];
        }
        out[row * OUTD + n] = a;
    }
}

// ---------------------------------------------------------------------------
extern "C" void kernel_launch(void* const* d_in, const int* in_sizes, int n_in,
                              void* d_out, int out_size, void* d_ws, size_t ws_size,
                              hipStream_t stream) {
    const float* x      = (const float*)d_in[0];
    const float* hidden = (const float*)d_in[1];
    const float* h0     = (const float*)d_in[2];
    const float* c0     = (const float*)d_in[3];
    const float* Wf1    = (const float*)d_in[4];
    const float* bf1    = (const float*)d_in[5];
    const float* Wf2    = (const float*)d_in[6];
    const float* bf2    = (const float*)d_in[7];
    const float* Wf3    = (const float*)d_in[8];
    const float* bf3    = (const float*)d_in[9];
    const float* Wg1    = (const float*)d_in[10];
    const float* bg1    = (const float*)d_in[11];
    const float* Wg2    = (const float*)d_in[12];
    const float* bg2    = (const float*)d_in[13];
    const float* Wg3    = (const float*)d_in[14];
    const float* bg3    = (const float*)d_in[15];
    const float* W_ih   = (const float*)d_in[16];
    const float* W_hh   = (const float*)d_in[17];
    const float* b_ih   = (const float*)d_in[18];
    const float* b_hh   = (const float*)d_in[19];
    const float* Wo1    = (const float*)d_in[20];
    const float* bo1    = (const float*)d_in[21];
    const float* Wo2    = (const float*)d_in[22];
    const float* bo2    = (const float*)d_in[23];

    float* wsf = (float*)d_ws;
    char*  wsb = (char*)d_ws;
    float*  A32  = wsf + WS_A32;
    float*  B32  = wsf + WS_B32;
    half_t* Whi  = (half_t*)(wsb + WS_WHI_B);
    half_t* Wlo  = (half_t*)(wsb + WS_WLO_B);
    float*  S    = wsf + WS_S;

    float* outp  = (float*)d_out;              // [512,64]
    float* hid1  = (float*)d_out + 32768;      // hidden_new [512,128]
    float* hid2  = (float*)d_out + 98304;      // hidden_new[None]
    float* cout  = (float*)d_out + 163840;     // c_new[None]

    hipMemsetAsync(S, 0, (size_t)NN * F2D * sizeof(float), stream);

    k0_transpose<<<dim3(92), dim3(256), 0, stream>>>(Wg1, Wg2, Wg3, W_ih, W_hh,
                                                     Wo1, Wo2, Wf3, wsf);

    k1_proj<<<dim3(128), dim3(256), 0, stream>>>(hidden, Wf1, bf1, Wf2,
                                                 A32, B32, Whi, Wlo);

    k2_pairwise<<<dim3(16, 32), dim3(512), 0, stream>>>(A32, B32, Whi, Wlo, bf2, S);

    k4_tail<<<dim3(128), dim3(256), 0, stream>>>(x, h0, c0, S, wsf,
                                                 bf3, bg1, bg2, bg3,
                                                 b_ih, b_hh, bo1, bo2,
                                                 outp, hid1, hid2, cout);
}

// Round 4
// 266.577 us; speedup vs baseline: 1.2089x; 1.2089x over previous
//
#include <hip/hip_runtime.h>
#include <hip/hip_bf16.h>

// ---------------------------------------------------------------------------
// RRN forward, MI355X.
//   k0: convert tail weights to f16 hi/lo pairs (row-major [N,K], MFMA-ready),
//       building W_cat = [W_ih | W_hh] along K.
//   k1: A32/B32 projections (fp32) + Wf2 -> f16 hi + f16 lo split
//   k2: pairwise MLP core (f16 MFMA hi/lo, h rounded once from fp32) [frozen]
//   k4: fused MFMA tail: SM -> g1 -> g2 -> g3 -> gates(+LSTM in-reg) -> o1 -> o2
//       32 blocks x 16 rows; weights streamed once per block; hi/lo activations
//       AND hi/lo weights (3-chain MFMA) => fp32-equivalent precision.
// ---------------------------------------------------------------------------

#define NN   512
#define HH   128
#define F1D  256
#define F2D  256
#define OUTD 64
#define ICHUNK 32

typedef _Float16 half_t;
typedef _Float16 half8 __attribute__((ext_vector_type(8)));
typedef float float4_t __attribute__((ext_vector_type(4)));
typedef float float8_t __attribute__((ext_vector_type(8)));

__device__ __forceinline__ float sigmoidf_(float x) {
    return 1.0f / (1.0f + __expf(-x));
}

// ---- workspace layout ----
// bytes: A32 0 (512K) | B32 524288 (512K) | Whi 1048576 (128K) | Wlo 1179648 (128K)
//        S 1310720 (512K) | tail f16 weights 1835008 (1.44M)
#define WS_TAIL_B 1835008
// f16-element offsets within tail region:
#define T3H 0
#define T3L 32768
#define G1H 65536
#define G1L 131072
#define G2H 196608
#define G2L 262144
#define G3H 327680
#define G3L 360448
#define CATH 393216
#define CATL 524288
#define O1H 655360
#define O1L 688128
#define O2H 720896
#define O2L 737280

// ---------------- k0: tail weight hi/lo conversion ----------------
// 368 blocks x 256 threads; 1024 elems/block; every matrix size is a
// multiple of 1024 so a block never straddles matrices.
__constant__ int c_cumblk[7] = {32, 96, 160, 192, 320, 352, 368};
__constant__ int c_hioff[7]  = {T3H, G1H, G2H, G3H, CATH, O1H, O2H};
__constant__ int c_cnt[7]    = {32768, 65536, 65536, 32768, 131072, 32768, 16384};

__global__ __launch_bounds__(256)
void k0_prep(const float* __restrict__ Wf3,
             const float* __restrict__ Wg1, const float* __restrict__ Wg2,
             const float* __restrict__ Wg3,
             const float* __restrict__ W_ih, const float* __restrict__ W_hh,
             const float* __restrict__ Wo1, const float* __restrict__ Wo2,
             half_t* __restrict__ tail) {
    const int t = threadIdx.x;
    const int bid = blockIdx.x;
    int m = 0;
    while (m < 6 && bid >= c_cumblk[m]) ++m;
    const int startblk = (m == 0) ? 0 : c_cumblk[m - 1];
    const int e0 = (bid - startblk) * 1024 + t * 4;

    float4_t v;
    if (m == 4) {  // CAT: n = e>>8, k = e&255 ; k<128 -> W_ih else W_hh
        const int n = e0 >> 8, k = e0 & 255;
        v = (k < 128) ? *(const float4_t*)(W_ih + n * 128 + k)
                      : *(const float4_t*)(W_hh + n * 128 + (k - 128));
    } else {
        const float* src;
        switch (m) {
            case 0: src = Wf3; break;
            case 1: src = Wg1; break;
            case 2: src = Wg2; break;
            case 3: src = Wg3; break;
            case 5: src = Wo1; break;
            default: src = Wo2; break;
        }
        v = *(const float4_t*)(src + e0);
    }
    half_t* hi = tail + c_hioff[m] + e0;
    half_t* lo = hi + c_cnt[m];
#pragma unroll
    for (int e = 0; e < 4; ++e) {
        half_t h = (half_t)v[e];
        hi[e] = h;
        lo[e] = (half_t)((v[e] - (float)h) * 4096.0f);
    }
}

// ---------------- k1: projections (fp32 out) + Wf2 hi/lo split ----------------
__global__ void k1_proj(const float* __restrict__ hidden,
                        const float* __restrict__ Wf1,
                        const float* __restrict__ bf1,
                        const float* __restrict__ Wf2,
                        float* __restrict__ A32,
                        float* __restrict__ B32,
                        half_t* __restrict__ Whi,
                        half_t* __restrict__ Wlo) {
    __shared__ float hid[4][HH];
    const int t = threadIdx.x;
    const int i0 = blockIdx.x * 4;
    for (int q = t; q < 4 * HH; q += 256)
        hid[q >> 7][q & 127] = hidden[(i0 + (q >> 7)) * HH + (q & 127)];
    __syncthreads();

    float accA[4], accB[4];
    const float b = bf1[t];
#pragma unroll
    for (int r = 0; r < 4; ++r) { accA[r] = b; accB[r] = 0.0f; }

    const float* wr = Wf1 + t * 256;
#pragma unroll 4
    for (int k = 0; k < HH; k += 4) {
        float4_t wa = *(const float4_t*)(wr + k);
        float4_t wb = *(const float4_t*)(wr + HH + k);
#pragma unroll
        for (int r = 0; r < 4; ++r) {
            const float* hp = &hid[r][k];
            accA[r] += wa[0]*hp[0] + wa[1]*hp[1] + wa[2]*hp[2] + wa[3]*hp[3];
            accB[r] += wb[0]*hp[0] + wb[1]*hp[1] + wb[2]*hp[2] + wb[3]*hp[3];
        }
    }
#pragma unroll
    for (int r = 0; r < 4; ++r) {
        A32[(i0 + r) * F1D + t] = accA[r];
        B32[(i0 + r) * F1D + t] = accB[r];
    }
    for (int q = t; q < 512; q += 256) {
        int idx = blockIdx.x * 512 + q;
        float wv = Wf2[idx];
        half_t hi = (half_t)wv;
        Whi[idx] = hi;
        Wlo[idx] = (half_t)((wv - (float)hi) * 4096.0f);
    }
}

// ---------------- k2: pairwise MLP core (frozen from round 2/3) ----------------
__global__ __launch_bounds__(512, 2)
void k2_pairwise(const float* __restrict__ A32,
                 const float* __restrict__ B32,
                 const half_t* __restrict__ Whi,
                 const half_t* __restrict__ Wlo,
                 const float* __restrict__ bf2,
                 float* __restrict__ S) {
    __shared__ float Alds[ICHUNK * F1D];   // 32 KB

    const int tid = threadIdx.x;
    const int lane = tid & 63;
    const int w = tid >> 6;           // wave 0..7
    const int l15 = lane & 15;
    const int g4 = lane >> 4;         // 0..3
    const int j0 = blockIdx.y * 16;
    const int i0 = blockIdx.x * ICHUNK;

    {
        const float4_t* src = (const float4_t*)(A32 + (size_t)i0 * F1D);
        float4_t* dst = (float4_t*)Alds;
        for (int q = tid; q < ICHUNK * F1D / 4; q += 512) dst[q] = src[q];
    }

    half8 Wh[2][8], Wl[2][8];
#pragma unroll
    for (int nt = 0; nt < 2; ++nt)
#pragma unroll
        for (int ks = 0; ks < 8; ++ks) {
            const size_t off = (size_t)(w*32 + nt*16 + l15) * F1D + ks*32 + g4*8;
            Wh[nt][ks] = *(const half8*)(Whi + off);
            Wl[nt][ks] = *(const half8*)(Wlo + off);
        }

    float8_t Bk[8];
#pragma unroll
    for (int ks = 0; ks < 8; ++ks)
        Bk[ks] = *(const float8_t*)(B32 + (size_t)(j0 + l15) * F1D + ks*32 + g4*8);

    float b2v[2];
#pragma unroll
    for (int nt = 0; nt < 2; ++nt) b2v[nt] = bf2[w*32 + nt*16 + l15];

    float4_t acc[2];
#pragma unroll
    for (int nt = 0; nt < 2; ++nt)
#pragma unroll
        for (int r = 0; r < 4; ++r) acc[nt][r] = 0.0f;

    __syncthreads();

    for (int io = 0; io < ICHUNK; ++io) {
        const float* Ar = Alds + io * F1D;

        float4_t C[2], Cl[2];
#pragma unroll
        for (int nt = 0; nt < 2; ++nt)
#pragma unroll
            for (int r = 0; r < 4; ++r) { C[nt][r] = 0.0f; Cl[nt][r] = 0.0f; }

#pragma unroll
        for (int ks = 0; ks < 8; ++ks) {
            float8_t a = *(const float8_t*)(Ar + ks*32 + g4*8);
            float8_t s = a + Bk[ks];
            half8 hf;
#pragma unroll
            for (int e = 0; e < 8; ++e) {
                float v = fmaxf(s[e], 0.0f);
                hf[e] = (half_t)v;
            }
            C[0]  = __builtin_amdgcn_mfma_f32_16x16x32_f16(hf, Wh[0][ks], C[0], 0, 0, 0);
            C[1]  = __builtin_amdgcn_mfma_f32_16x16x32_f16(hf, Wh[1][ks], C[1], 0, 0, 0);
            Cl[0] = __builtin_amdgcn_mfma_f32_16x16x32_f16(hf, Wl[0][ks], Cl[0], 0, 0, 0);
            Cl[1] = __builtin_amdgcn_mfma_f32_16x16x32_f16(hf, Wl[1][ks], Cl[1], 0, 0, 0);
        }
#pragma unroll
        for (int nt = 0; nt < 2; ++nt) {
#pragma unroll
            for (int r = 0; r < 4; ++r) {
                float v = fmaf(Cl[nt][r], 2.44140625e-4f, C[nt][r]) + b2v[nt];
                acc[nt][r] += fmaxf(v, 0.0f);
            }
        }
    }

#pragma unroll
    for (int nt = 0; nt < 2; ++nt)
#pragma unroll
        for (int r = 0; r < 4; ++r)
            atomicAdd(&S[(size_t)(j0 + g4*4 + r) * F2D + w*32 + nt*16 + l15], acc[nt][r]);
}

// ---------------- k4: fused MFMA tail ----------------
// 32 blocks x 512 threads (8 waves); block owns rows [blockIdx.x*16, +16).
// Per layer: A = activations (fp32 in LDS, hi/lo f16 split at load),
// B = weights (hi/lo f16 from ws), 3-chain MFMA => ~fp32 precision.
#define AST 260   // LDS activation row stride (floats): 16B-aligned rows

template<int NT, int NKS>
__device__ __forceinline__ void frag_gemm(const float* __restrict__ aPtr,
                                          const half_t* __restrict__ Whi,
                                          const half_t* __restrict__ Wlo,
                                          const int* wOff,
                                          float4_t* Chi, float4_t* Clo) {
#pragma unroll
    for (int ks = 0; ks < NKS; ++ks) {
        float4_t a0 = *(const float4_t*)(aPtr + ks * 32);
        float4_t a1 = *(const float4_t*)(aPtr + ks * 32 + 4);
        half8 ah, al;
#pragma unroll
        for (int e = 0; e < 4; ++e) {
            half_t h0 = (half_t)a0[e];
            ah[e] = h0; al[e] = (half_t)((a0[e] - (float)h0) * 4096.0f);
            half_t h1 = (half_t)a1[e];
            ah[4+e] = h1; al[4+e] = (half_t)((a1[e] - (float)h1) * 4096.0f);
        }
#pragma unroll
        for (int nt = 0; nt < NT; ++nt) {
            half8 wh = *(const half8*)(Whi + wOff[nt] + ks * 32);
            half8 wl = *(const half8*)(Wlo + wOff[nt] + ks * 32);
            Chi[nt] = __builtin_amdgcn_mfma_f32_16x16x32_f16(ah, wh, Chi[nt], 0, 0, 0);
            Clo[nt] = __builtin_amdgcn_mfma_f32_16x16x32_f16(ah, wl, Clo[nt], 0, 0, 0);
            Clo[nt] = __builtin_amdgcn_mfma_f32_16x16x32_f16(al, wh, Clo[nt], 0, 0, 0);
        }
    }
}

#define HL_INV 2.44140625e-4f

__global__ __launch_bounds__(512)
void k4_tail(const float* __restrict__ S,
             const float* __restrict__ x,
             const float* __restrict__ h0,
             const float* __restrict__ c0,
             const half_t* __restrict__ tail,
             const float* __restrict__ bf3,
             const float* __restrict__ bg1, const float* __restrict__ bg2,
             const float* __restrict__ bg3,
             const float* __restrict__ b_ih, const float* __restrict__ b_hh,
             const float* __restrict__ bo1, const float* __restrict__ bo2,
             float* __restrict__ out,
             float* __restrict__ hid_out,
             float* __restrict__ h_out,
             float* __restrict__ c_out) {
    __shared__ float bufA[16 * AST];   // x | SM  ->  input_g | h0
    __shared__ float bufB[16 * AST];   // g1      ->  o1
    __shared__ float bufC[16 * AST];   // S       ->  g2  ->  h
    const int tid = threadIdx.x;
    const int lane = tid & 63;
    const int w = tid >> 6;
    const int l15 = lane & 15;
    const int g4 = lane >> 4;
    const int r0 = blockIdx.x * 16;

    // ---- stage S -> bufC, x -> bufA[:,0:128] ----
    for (int q = tid; q < 16 * 256; q += 512)
        bufC[(q >> 8) * AST + (q & 255)] = S[(size_t)(r0 + (q >> 8)) * 256 + (q & 255)];
    for (int q = tid; q < 16 * 128; q += 512)
        bufA[(q >> 7) * AST + (q & 127)] = x[(r0 + (q >> 7)) * 128 + (q & 127)];
    __syncthreads();

    const float* aFrag;
    int wOff[4];
    float4_t Chi[4], Clo[4];

    // ---- SM: [16,256] @ T3[128,256]^T + 512*bf3 -> bufA[:,128:256] ----
    {
        const int n = w * 16 + l15;
        wOff[0] = n * 256 + g4 * 8;
        Chi[0] = float4_t{0,0,0,0}; Clo[0] = float4_t{0,0,0,0};
        aFrag = bufC + l15 * AST + g4 * 8;
        frag_gemm<1, 8>(aFrag, tail + T3H, tail + T3L, wOff, Chi, Clo);
        const float b = 512.0f * bf3[n];
#pragma unroll
        for (int r = 0; r < 4; ++r)
            bufA[(g4 * 4 + r) * AST + 128 + n] = Chi[0][r] + Clo[0][r] * HL_INV + b;
    }
    __syncthreads();

    // ---- g1: [16,256] @ G1[256,256]^T + bg1, relu -> bufB ----
    {
#pragma unroll
        for (int nt = 0; nt < 2; ++nt) {
            wOff[nt] = (w * 32 + nt * 16 + l15) * 256 + g4 * 8;
            Chi[nt] = float4_t{0,0,0,0}; Clo[nt] = float4_t{0,0,0,0};
        }
        aFrag = bufA + l15 * AST + g4 * 8;
        frag_gemm<2, 8>(aFrag, tail + G1H, tail + G1L, wOff, Chi, Clo);
#pragma unroll
        for (int nt = 0; nt < 2; ++nt) {
            const int n = w * 32 + nt * 16 + l15;
            const float b = bg1[n];
#pragma unroll
            for (int r = 0; r < 4; ++r)
                bufB[(g4 * 4 + r) * AST + n] = fmaxf(Chi[nt][r] + Clo[nt][r] * HL_INV + b, 0.0f);
        }
    }
    __syncthreads();

    // ---- g2: bufB @ G2^T + bg2, relu -> bufC ; also stage h0 -> bufA[:,128:256] ----
    {
#pragma unroll
        for (int nt = 0; nt < 2; ++nt) {
            wOff[nt] = (w * 32 + nt * 16 + l15) * 256 + g4 * 8;
            Chi[nt] = float4_t{0,0,0,0}; Clo[nt] = float4_t{0,0,0,0};
        }
        aFrag = bufB + l15 * AST + g4 * 8;
        frag_gemm<2, 8>(aFrag, tail + G2H, tail + G2L, wOff, Chi, Clo);
#pragma unroll
        for (int nt = 0; nt < 2; ++nt) {
            const int n = w * 32 + nt * 16 + l15;
            const float b = bg2[n];
#pragma unroll
            for (int r = 0; r < 4; ++r)
                bufC[(g4 * 4 + r) * AST + n] = fmaxf(Chi[nt][r] + Clo[nt][r] * HL_INV + b, 0.0f);
        }
        for (int q = tid; q < 16 * 128; q += 512)
            bufA[(q >> 7) * AST + 128 + (q & 127)] = h0[(r0 + (q >> 7)) * 128 + (q & 127)];
    }
    __syncthreads();

    // ---- g3: bufC @ G3[128,256]^T + bg3 -> bufA[:,0:128] ----
    {
        const int n = w * 16 + l15;
        wOff[0] = n * 256 + g4 * 8;
        Chi[0] = float4_t{0,0,0,0}; Clo[0] = float4_t{0,0,0,0};
        aFrag = bufC + l15 * AST + g4 * 8;
        frag_gemm<1, 8>(aFrag, tail + G3H, tail + G3L, wOff, Chi, Clo);
        const float b = bg3[n];
#pragma unroll
        for (int r = 0; r < 4; ++r)
            bufA[(g4 * 4 + r) * AST + n] = Chi[0][r] + Clo[0][r] * HL_INV + b;
    }
    __syncthreads();

    // ---- gates: bufA([input_g | h0]) @ CAT[512,256]^T + b_ih + b_hh ----
    // nt -> n = w*16 + nt*128 + l15  => thread holds i,f,g,o for one hidden unit
    {
#pragma unroll
        for (int nt = 0; nt < 4; ++nt) {
            wOff[nt] = (w * 16 + nt * 128 + l15) * 256 + g4 * 8;
            Chi[nt] = float4_t{0,0,0,0}; Clo[nt] = float4_t{0,0,0,0};
        }
        aFrag = bufA + l15 * AST + g4 * 8;
        frag_gemm<4, 8>(aFrag, tail + CATH, tail + CATL, wOff, Chi, Clo);

        const int nh = w * 16 + l15;
        float bi = b_ih[nh]       + b_hh[nh];
        float bf = b_ih[128 + nh] + b_hh[128 + nh];
        float bg = b_ih[256 + nh] + b_hh[256 + nh];
        float bo = b_ih[384 + nh] + b_hh[384 + nh];
#pragma unroll
        for (int r = 0; r < 4; ++r) {
            const int row = r0 + g4 * 4 + r;
            float gi = sigmoidf_(Chi[0][r] + Clo[0][r] * HL_INV + bi);
            float gf = sigmoidf_(Chi[1][r] + Clo[1][r] * HL_INV + bf);
            float gg = tanhf(    Chi[2][r] + Clo[2][r] * HL_INV + bg);
            float go = sigmoidf_(Chi[3][r] + Clo[3][r] * HL_INV + bo);
            float c = gf * c0[row * 128 + nh] + gi * gg;
            float h = go * tanhf(c);
            bufC[(g4 * 4 + r) * AST + nh] = h;
            hid_out[row * 128 + nh] = h;
            h_out[row * 128 + nh]   = h;
            c_out[row * 128 + nh]   = c;
        }
    }
    __syncthreads();

    // ---- o1: bufC[:,0:128] @ O1[256,128]^T + bo1, relu -> bufB ----
    {
#pragma unroll
        for (int nt = 0; nt < 2; ++nt) {
            wOff[nt] = (w * 32 + nt * 16 + l15) * 128 + g4 * 8;
            Chi[nt] = float4_t{0,0,0,0}; Clo[nt] = float4_t{0,0,0,0};
        }
        aFrag = bufC + l15 * AST + g4 * 8;
        frag_gemm<2, 4>(aFrag, tail + O1H, tail + O1L, wOff, Chi, Clo);
#pragma unroll
        for (int nt = 0; nt < 2; ++nt) {
            const int n = w * 32 + nt * 16 + l15;
            const float b = bo1[n];
#pragma unroll
            for (int r = 0; r < 4; ++r)
                bufB[(g4 * 4 + r) * AST + n] = fmaxf(Chi[nt][r] + Clo[nt][r] * HL_INV + b, 0.0f);
        }
    }
    __syncthreads();

    // ---- o2: bufB @ O2[64,256]^T + bo2 -> out (waves 0-3 only) ----
    if (w < 4) {
        const int n = w * 16 + l15;
        wOff[0] = n * 256 + g4 * 8;
        Chi[0] = float4_t{0,0,0,0}; Clo[0] = float4_t{0,0,0,0};
        aFrag = bufB + l15 * AST + g4 * 8;
        frag_gemm<1, 8>(aFrag, tail + O2H, tail + O2L, wOff, Chi, Clo);
        const float b = bo2[n];
#pragma unroll
        for (int r = 0; r < 4; ++r)
            out[(r0 + g4 * 4 + r) * OUTD + n] = Chi[0][r] + Clo[0][r] * HL_INV + b;
    }
}

// ---------------------------------------------------------------------------
extern "C" void kernel_launch(void* const* d_in, const int* in_sizes, int n_in,
                              void* d_out, int out_size, void* d_ws, size_t ws_size,
                              hipStream_t stream) {
    const float* x      = (const float*)d_in[0];
    const float* hidden = (const float*)d_in[1];
    const float* h0     = (const float*)d_in[2];
    const float* c0     = (const float*)d_in[3];
    const float* Wf1    = (const float*)d_in[4];
    const float* bf1    = (const float*)d_in[5];
    const float* Wf2    = (const float*)d_in[6];
    const float* bf2    = (const float*)d_in[7];
    const float* Wf3    = (const float*)d_in[8];
    const float* bf3    = (const float*)d_in[9];
    const float* Wg1    = (const float*)d_in[10];
    const float* bg1    = (const float*)d_in[11];
    const float* Wg2    = (const float*)d_in[12];
    const float* bg2    = (const float*)d_in[13];
    const float* Wg3    = (const float*)d_in[14];
    const float* bg3    = (const float*)d_in[15];
    const float* W_ih   = (const float*)d_in[16];
    const float* W_hh   = (const float*)d_in[17];
    const float* b_ih   = (const float*)d_in[18];
    const float* b_hh   = (const float*)d_in[19];
    const float* Wo1    = (const float*)d_in[20];
    const float* bo1    = (const float*)d_in[21];
    const float* Wo2    = (const float*)d_in[22];
    const float* bo2    = (const float*)d_in[23];

    char* wsb = (char*)d_ws;
    float*  A32  = (float*)(wsb + 0);
    float*  B32  = (float*)(wsb + 524288);
    half_t* Whi  = (half_t*)(wsb + 1048576);
    half_t* Wlo  = (half_t*)(wsb + 1179648);
    float*  S    = (float*)(wsb + 1310720);
    half_t* tail = (half_t*)(wsb + WS_TAIL_B);

    float* outp  = (float*)d_out;              // [512,64]
    float* hid1  = (float*)d_out + 32768;      // hidden_new [512,128]
    float* hid2  = (float*)d_out + 98304;      // hidden_new[None]
    float* cout  = (float*)d_out + 163840;     // c_new[None]

    hipMemsetAsync(S, 0, (size_t)NN * F2D * sizeof(float), stream);

    k0_prep<<<dim3(368), dim3(256), 0, stream>>>(Wf3, Wg1, Wg2, Wg3,
                                                 W_ih, W_hh, Wo1, Wo2, tail);

    k1_proj<<<dim3(128), dim3(256), 0, stream>>>(hidden, Wf1, bf1, Wf2,
                                                 A32, B32, Whi, Wlo);

    k2_pairwise<<<dim3(16, 32), dim3(512), 0, stream>>>(A32, B32, Whi, Wlo, bf2, S);

    k4_tail<<<dim3(32), dim3(512), 0, stream>>>(S, x, h0, c0, tail,
                                                bf3, bg1, bg2, bg3,
                                                b_ih, b_hh, bo1, bo2,
                                                outp, hid1, hid2, cout);
}

// Round 5
// 223.768 us; speedup vs baseline: 1.4401x; 1.1913x over previous
//
#include <hip/hip_runtime.h>
#include <hip/hip_bf16.h>

// ---------------------------------------------------------------------------
// RRN forward, MI355X.
//   k0: pack tail weights into MFMA B-fragment stream order, f16 hi/lo.
//   k1: A32/B32 projections (fp32) + Wf2 -> f16 hi + f16 lo (row-major).
//   k2: pairwise MLP: producer/consumer h-staging. Wave w computes h k-slice
//       ks=w (relu(A+B) fp32 -> f16 once), ds_writes fragment to LDS dbuf;
//       all waves then MFMA it against their private W hi/lo fragments.
//   k4: fused tail (SM->g1->g2->g3->LSTM->o1->o2), fragment-coalesced weights.
// ---------------------------------------------------------------------------

#define NN   512
#define HH   128
#define F1D  256
#define F2D  256
#define OUTD 64
#define ICHUNK 64

typedef _Float16 half_t;
typedef _Float16 half4 __attribute__((ext_vector_type(4)));
typedef _Float16 half8 __attribute__((ext_vector_type(8)));
typedef float float4_t __attribute__((ext_vector_type(4)));
typedef float float8_t __attribute__((ext_vector_type(8)));

__device__ __forceinline__ float sigmoidf_(float x) {
    return 1.0f / (1.0f + __expf(-x));
}

#define HL_INV 2.44140625e-4f

// ---- workspace layout (bytes) ----
// A32 0 (512K) | B32 524288 (512K) | Whi 1048576 (128K) | Wlo 1179648 (128K)
// S 1310720 (512K) | tail f16 frag-packed weights 1835008 (1.44M)
#define WS_TAIL_B 1835008
// f16-element offsets within tail region (hi base; lo = hi + cnt):
#define T3H 0
#define G1H 65536
#define G2H 196608
#define G3H 327680
#define CATH 393216
#define O1H 655360
#define O2H 720896

// ---------------- k0: tail weight hi/lo conversion + fragment packing ----------------
// 368 blocks x 256 threads; 1024 elems/block, 4 elems/thread.
// frag layout per matrix [N][K]: idx = panel*(16K) + ks*512 + (g4*16+l15)*8 + e
__constant__ int c_cumblk[7] = {32, 96, 160, 192, 320, 352, 368};
__constant__ int c_hioff[7]  = {T3H, G1H, G2H, G3H, CATH, O1H, O2H};
__constant__ int c_cnt[7]    = {32768, 65536, 65536, 32768, 131072, 32768, 16384};
__constant__ int c_K[7]      = {256, 256, 256, 256, 256, 128, 256};

__global__ __launch_bounds__(256)
void k0_prep(const float* __restrict__ Wf3,
             const float* __restrict__ Wg1, const float* __restrict__ Wg2,
             const float* __restrict__ Wg3,
             const float* __restrict__ W_ih, const float* __restrict__ W_hh,
             const float* __restrict__ Wo1, const float* __restrict__ Wo2,
             half_t* __restrict__ tail) {
    const int t = threadIdx.x;
    const int bid = blockIdx.x;
    int m = 0;
    while (m < 6 && bid >= c_cumblk[m]) ++m;
    const int startblk = (m == 0) ? 0 : c_cumblk[m - 1];
    const int e0 = (bid - startblk) * 1024 + t * 4;
    const int K = c_K[m];

    float4_t v;
    if (m == 4) {  // CAT: K=256, k<128 -> W_ih else W_hh
        const int n = e0 >> 8, k = e0 & 255;
        v = (k < 128) ? *(const float4_t*)(W_ih + n * 128 + k)
                      : *(const float4_t*)(W_hh + n * 128 + (k - 128));
    } else {
        const float* src;
        switch (m) {
            case 0: src = Wf3; break;
            case 1: src = Wg1; break;
            case 2: src = Wg2; break;
            case 3: src = Wg3; break;
            case 5: src = Wo1; break;
            default: src = Wo2; break;
        }
        v = *(const float4_t*)(src + e0);
    }
    // fragment-scatter destination
    const int n = e0 / K, k = e0 % K;
    const int panel = n >> 4, l15 = n & 15;
    const int ks = k >> 5, g4 = (k >> 3) & 3, e = k & 7;
    const int fidx = panel * (K << 4) + ks * 512 + ((g4 << 4) + l15) * 8 + e;

    half4 hv, lv;
#pragma unroll
    for (int q = 0; q < 4; ++q) {
        half_t h = (half_t)v[q];
        hv[q] = h;
        lv[q] = (half_t)((v[q] - (float)h) * 4096.0f);
    }
    *(half4*)(tail + c_hioff[m] + fidx) = hv;
    *(half4*)(tail + c_hioff[m] + c_cnt[m] + fidx) = lv;
}

// ---------------- k1: projections (fp32 out) + Wf2 hi/lo split ----------------
__global__ void k1_proj(const float* __restrict__ hidden,
                        const float* __restrict__ Wf1,
                        const float* __restrict__ bf1,
                        const float* __restrict__ Wf2,
                        float* __restrict__ A32,
                        float* __restrict__ B32,
                        half_t* __restrict__ Whi,
                        half_t* __restrict__ Wlo) {
    __shared__ float hid[4][HH];
    const int t = threadIdx.x;
    const int i0 = blockIdx.x * 4;
    for (int q = t; q < 4 * HH; q += 256)
        hid[q >> 7][q & 127] = hidden[(i0 + (q >> 7)) * HH + (q & 127)];
    __syncthreads();

    float accA[4], accB[4];
    const float b = bf1[t];
#pragma unroll
    for (int r = 0; r < 4; ++r) { accA[r] = b; accB[r] = 0.0f; }

    const float* wr = Wf1 + t * 256;
#pragma unroll 4
    for (int k = 0; k < HH; k += 4) {
        float4_t wa = *(const float4_t*)(wr + k);
        float4_t wb = *(const float4_t*)(wr + HH + k);
#pragma unroll
        for (int r = 0; r < 4; ++r) {
            const float* hp = &hid[r][k];
            accA[r] += wa[0]*hp[0] + wa[1]*hp[1] + wa[2]*hp[2] + wa[3]*hp[3];
            accB[r] += wb[0]*hp[0] + wb[1]*hp[1] + wb[2]*hp[2] + wb[3]*hp[3];
        }
    }
#pragma unroll
    for (int r = 0; r < 4; ++r) {
        A32[(i0 + r) * F1D + t] = accA[r];
        B32[(i0 + r) * F1D + t] = accB[r];
    }
    for (int q = t; q < 512; q += 256) {
        int idx = blockIdx.x * 512 + q;
        float wv = Wf2[idx];
        half_t hi = (half_t)wv;
        Whi[idx] = hi;
        Wlo[idx] = (half_t)((wv - (float)hi) * 4096.0f);
    }
}

// ---------------- k2: pairwise MLP core, producer/consumer h staging ----------------
// grid (8 i-chunks, 32 j-tiles) x 512 threads (8 waves), 1 block/CU.
// wave w: produces h fragment for k-slice ks=w; consumes all 8 for its n-range
// [w*32, w*32+32). M-tile = 16 j. Double-buffered 8KB h staging in LDS.
__global__ __launch_bounds__(512, 2)
void k2_pairwise(const float* __restrict__ A32,
                 const float* __restrict__ B32,
                 const half_t* __restrict__ Whi,
                 const half_t* __restrict__ Wlo,
                 const float* __restrict__ bf2,
                 float* __restrict__ S) {
    __shared__ half_t hbuf[2][8][512];   // [dbuf][ks][lane*8] = 2 x 8KB

    const int tid = threadIdx.x;
    const int lane = tid & 63;
    const int w = tid >> 6;           // wave 0..7
    const int l15 = lane & 15;
    const int g4 = lane >> 4;         // 0..3
    const int j0 = blockIdx.y * 16;
    const int i0 = blockIdx.x * ICHUNK;

    // persistent W fragments: n = w*32 + nt*16 + l15, k = ks*32 + g4*8 + e
    half8 Wh[2][8], Wl[2][8];
#pragma unroll
    for (int nt = 0; nt < 2; ++nt)
#pragma unroll
        for (int ks = 0; ks < 8; ++ks) {
            const size_t off = (size_t)(w*32 + nt*16 + l15) * F1D + ks*32 + g4*8;
            Wh[nt][ks] = *(const half8*)(Whi + off);
            Wl[nt][ks] = *(const half8*)(Wlo + off);
        }

    // producer's B slice: B[j=l15][k = w*32 + g4*8 .. +8]
    const float8_t Bw = *(const float8_t*)(B32 + (size_t)(j0 + l15) * F1D + w*32 + g4*8);

    float b2v[2];
#pragma unroll
    for (int nt = 0; nt < 2; ++nt) b2v[nt] = bf2[w*32 + nt*16 + l15];

    float4_t acc[2];
#pragma unroll
    for (int nt = 0; nt < 2; ++nt)
#pragma unroll
        for (int r = 0; r < 4; ++r) acc[nt][r] = 0.0f;

    // prologue: produce h(0)
    {
        float8_t a = *(const float8_t*)(A32 + (size_t)i0 * F1D + w*32 + g4*8);
        float8_t s = a + Bw;
        half8 hf;
#pragma unroll
        for (int e = 0; e < 8; ++e) hf[e] = (half_t)fmaxf(s[e], 0.0f);
        *(half8*)&hbuf[0][w][lane * 8] = hf;
    }
    __syncthreads();

    int p = 0;
    for (int io = 0; io < ICHUNK; ++io) {
        // prefetch next A slice early (latency hides under MFMA)
        float8_t a;
        if (io + 1 < ICHUNK)
            a = *(const float8_t*)(A32 + (size_t)(i0 + io + 1) * F1D + w*32 + g4*8);

        // MFMA phase on hbuf[p]
        float4_t C[2], Cl[2];
#pragma unroll
        for (int nt = 0; nt < 2; ++nt)
#pragma unroll
            for (int r = 0; r < 4; ++r) { C[nt][r] = 0.0f; Cl[nt][r] = 0.0f; }

#pragma unroll
        for (int ks = 0; ks < 8; ++ks) {
            half8 hf = *(const half8*)&hbuf[p][ks][lane * 8];
            C[0]  = __builtin_amdgcn_mfma_f32_16x16x32_f16(hf, Wh[0][ks], C[0], 0, 0, 0);
            C[1]  = __builtin_amdgcn_mfma_f32_16x16x32_f16(hf, Wh[1][ks], C[1], 0, 0, 0);
            Cl[0] = __builtin_amdgcn_mfma_f32_16x16x32_f16(hf, Wl[0][ks], Cl[0], 0, 0, 0);
            Cl[1] = __builtin_amdgcn_mfma_f32_16x16x32_f16(hf, Wl[1][ks], Cl[1], 0, 0, 0);
        }

        // produce h(io+1) into hbuf[p^1]
        if (io + 1 < ICHUNK) {
            float8_t s = a + Bw;
            half8 hf;
#pragma unroll
            for (int e = 0; e < 8; ++e) hf[e] = (half_t)fmaxf(s[e], 0.0f);
            *(half8*)&hbuf[p ^ 1][w][lane * 8] = hf;
        }

        // epilogue: h2 = relu(C + Cl/4096 + bf2), accumulate over i
#pragma unroll
        for (int nt = 0; nt < 2; ++nt) {
#pragma unroll
            for (int r = 0; r < 4; ++r) {
                float v = fmaf(Cl[nt][r], HL_INV, C[nt][r]) + b2v[nt];
                acc[nt][r] += fmaxf(v, 0.0f);
            }
        }
        __syncthreads();
        p ^= 1;
    }

    // C layout: col = l15 (n), row = g4*4 + r (jj)
#pragma unroll
    for (int nt = 0; nt < 2; ++nt)
#pragma unroll
        for (int r = 0; r < 4; ++r)
            atomicAdd(&S[(size_t)(j0 + g4*4 + r) * F2D + w*32 + nt*16 + l15], acc[nt][r]);
}

// ---------------- k4: fused MFMA tail, fragment-coalesced weights ----------------
#define AST 260   // LDS activation row stride (floats)

template<int NT, int NKS>
__device__ __forceinline__ void frag_gemm(const float* __restrict__ aPtr,
                                          const half_t* __restrict__ WhF,
                                          const half_t* __restrict__ WlF,
                                          const int* pB, int lane8,
                                          float4_t* Chi, float4_t* Clo) {
#pragma unroll
    for (int ks = 0; ks < NKS; ++ks) {
        float4_t a0 = *(const float4_t*)(aPtr + ks * 32);
        float4_t a1 = *(const float4_t*)(aPtr + ks * 32 + 4);
        half8 ah, al;
#pragma unroll
        for (int e = 0; e < 4; ++e) {
            half_t h0 = (half_t)a0[e];
            ah[e] = h0; al[e] = (half_t)((a0[e] - (float)h0) * 4096.0f);
            half_t h1 = (half_t)a1[e];
            ah[4+e] = h1; al[4+e] = (half_t)((a1[e] - (float)h1) * 4096.0f);
        }
#pragma unroll
        for (int nt = 0; nt < NT; ++nt) {
            half8 wh = *(const half8*)(WhF + pB[nt] + ks * 512 + lane8);
            half8 wl = *(const half8*)(WlF + pB[nt] + ks * 512 + lane8);
            Chi[nt] = __builtin_amdgcn_mfma_f32_16x16x32_f16(ah, wh, Chi[nt], 0, 0, 0);
            Clo[nt] = __builtin_amdgcn_mfma_f32_16x16x32_f16(ah, wl, Clo[nt], 0, 0, 0);
            Clo[nt] = __builtin_amdgcn_mfma_f32_16x16x32_f16(al, wh, Clo[nt], 0, 0, 0);
        }
    }
}

__global__ __launch_bounds__(512)
void k4_tail(const float* __restrict__ S,
             const float* __restrict__ x,
             const float* __restrict__ h0,
             const float* __restrict__ c0,
             const half_t* __restrict__ tail,
             const float* __restrict__ bf3,
             const float* __restrict__ bg1, const float* __restrict__ bg2,
             const float* __restrict__ bg3,
             const float* __restrict__ b_ih, const float* __restrict__ b_hh,
             const float* __restrict__ bo1, const float* __restrict__ bo2,
             float* __restrict__ out,
             float* __restrict__ hid_out,
             float* __restrict__ h_out,
             float* __restrict__ c_out) {
    __shared__ float bufA[16 * AST];   // x | SM  ->  input_g | h0
    __shared__ float bufB[16 * AST];   // g1      ->  o1
    __shared__ float bufC[16 * AST];   // S       ->  g2  ->  h
    const int tid = threadIdx.x;
    const int lane = tid & 63;
    const int w = tid >> 6;
    const int l15 = lane & 15;
    const int g4 = lane >> 4;
    const int r0 = blockIdx.x * 16;
    const int lane8 = lane * 8;

    for (int q = tid; q < 16 * 256; q += 512)
        bufC[(q >> 8) * AST + (q & 255)] = S[(size_t)(r0 + (q >> 8)) * 256 + (q & 255)];
    for (int q = tid; q < 16 * 128; q += 512)
        bufA[(q >> 7) * AST + (q & 127)] = x[(r0 + (q >> 7)) * 128 + (q & 127)];
    __syncthreads();

    const float* aFrag;
    int pB[4];
    float4_t Chi[4], Clo[4];

    // ---- SM: bufC @ Wf3[128,256]^T + 512*bf3 -> bufA[:,128:256] ----
    {
        const int n = w * 16 + l15;
        pB[0] = w * 4096;
        Chi[0] = float4_t{0,0,0,0}; Clo[0] = float4_t{0,0,0,0};
        aFrag = bufC + l15 * AST + g4 * 8;
        frag_gemm<1, 8>(aFrag, tail + T3H, tail + T3H + 32768, pB, lane8, Chi, Clo);
        const float b = 512.0f * bf3[n];
#pragma unroll
        for (int r = 0; r < 4; ++r)
            bufA[(g4 * 4 + r) * AST + 128 + n] = Chi[0][r] + Clo[0][r] * HL_INV + b;
    }
    __syncthreads();

    // ---- g1: bufA @ Wg1[256,256]^T + bg1, relu -> bufB ----
    {
        pB[0] = (w * 2) * 4096; pB[1] = (w * 2 + 1) * 4096;
        Chi[0] = float4_t{0,0,0,0}; Clo[0] = float4_t{0,0,0,0};
        Chi[1] = float4_t{0,0,0,0}; Clo[1] = float4_t{0,0,0,0};
        aFrag = bufA + l15 * AST + g4 * 8;
        frag_gemm<2, 8>(aFrag, tail + G1H, tail + G1H + 65536, pB, lane8, Chi, Clo);
#pragma unroll
        for (int nt = 0; nt < 2; ++nt) {
            const int n = w * 32 + nt * 16 + l15;
            const float b = bg1[n];
#pragma unroll
            for (int r = 0; r < 4; ++r)
                bufB[(g4 * 4 + r) * AST + n] = fmaxf(Chi[nt][r] + Clo[nt][r] * HL_INV + b, 0.0f);
        }
    }
    __syncthreads();

    // ---- g2: bufB @ Wg2^T + bg2, relu -> bufC ; stage h0 -> bufA[:,128:256] ----
    {
        pB[0] = (w * 2) * 4096; pB[1] = (w * 2 + 1) * 4096;
        Chi[0] = float4_t{0,0,0,0}; Clo[0] = float4_t{0,0,0,0};
        Chi[1] = float4_t{0,0,0,0}; Clo[1] = float4_t{0,0,0,0};
        aFrag = bufB + l15 * AST + g4 * 8;
        frag_gemm<2, 8>(aFrag, tail + G2H, tail + G2H + 65536, pB, lane8, Chi, Clo);
#pragma unroll
        for (int nt = 0; nt < 2; ++nt) {
            const int n = w * 32 + nt * 16 + l15;
            const float b = bg2[n];
#pragma unroll
            for (int r = 0; r < 4; ++r)
                bufC[(g4 * 4 + r) * AST + n] = fmaxf(Chi[nt][r] + Clo[nt][r] * HL_INV + b, 0.0f);
        }
        for (int q = tid; q < 16 * 128; q += 512)
            bufA[(q >> 7) * AST + 128 + (q & 127)] = h0[(r0 + (q >> 7)) * 128 + (q & 127)];
    }
    __syncthreads();

    // ---- g3: bufC @ Wg3[128,256]^T + bg3 -> bufA[:,0:128] ----
    {
        const int n = w * 16 + l15;
        pB[0] = w * 4096;
        Chi[0] = float4_t{0,0,0,0}; Clo[0] = float4_t{0,0,0,0};
        aFrag = bufC + l15 * AST + g4 * 8;
        frag_gemm<1, 8>(aFrag, tail + G3H, tail + G3H + 32768, pB, lane8, Chi, Clo);
        const float b = bg3[n];
#pragma unroll
        for (int r = 0; r < 4; ++r)
            bufA[(g4 * 4 + r) * AST + n] = Chi[0][r] + Clo[0][r] * HL_INV + b;
    }
    __syncthreads();

    // ---- gates: bufA([input_g | h0]) @ CAT[512,256]^T; LSTM in-register ----
    {
#pragma unroll
        for (int nt = 0; nt < 4; ++nt) {
            pB[nt] = (w + nt * 8) * 4096;
            Chi[nt] = float4_t{0,0,0,0}; Clo[nt] = float4_t{0,0,0,0};
        }
        aFrag = bufA + l15 * AST + g4 * 8;
        frag_gemm<4, 8>(aFrag, tail + CATH, tail + CATH + 131072, pB, lane8, Chi, Clo);

        const int nh = w * 16 + l15;
        float bi = b_ih[nh]       + b_hh[nh];
        float bf = b_ih[128 + nh] + b_hh[128 + nh];
        float bg = b_ih[256 + nh] + b_hh[256 + nh];
        float bo = b_ih[384 + nh] + b_hh[384 + nh];
#pragma unroll
        for (int r = 0; r < 4; ++r) {
            const int row = r0 + g4 * 4 + r;
            float gi = sigmoidf_(Chi[0][r] + Clo[0][r] * HL_INV + bi);
            float gf = sigmoidf_(Chi[1][r] + Clo[1][r] * HL_INV + bf);
            float gg = tanhf(    Chi[2][r] + Clo[2][r] * HL_INV + bg);
            float go = sigmoidf_(Chi[3][r] + Clo[3][r] * HL_INV + bo);
            float c = gf * c0[row * 128 + nh] + gi * gg;
            float h = go * tanhf(c);
            bufC[(g4 * 4 + r) * AST + nh] = h;
            hid_out[row * 128 + nh] = h;
            h_out[row * 128 + nh]   = h;
            c_out[row * 128 + nh]   = c;
        }
    }
    __syncthreads();

    // ---- o1: bufC[:,0:128] @ Wo1[256,128]^T + bo1, relu -> bufB ----
    {
        pB[0] = (w * 2) * 2048; pB[1] = (w * 2 + 1) * 2048;
        Chi[0] = float4_t{0,0,0,0}; Clo[0] = float4_t{0,0,0,0};
        Chi[1] = float4_t{0,0,0,0}; Clo[1] = float4_t{0,0,0,0};
        aFrag = bufC + l15 * AST + g4 * 8;
        frag_gemm<2, 4>(aFrag, tail + O1H, tail + O1H + 32768, pB, lane8, Chi, Clo);
#pragma unroll
        for (int nt = 0; nt < 2; ++nt) {
            const int n = w * 32 + nt * 16 + l15;
            const float b = bo1[n];
#pragma unroll
            for (int r = 0; r < 4; ++r)
                bufB[(g4 * 4 + r) * AST + n] = fmaxf(Chi[nt][r] + Clo[nt][r] * HL_INV + b, 0.0f);
        }
    }
    __syncthreads();

    // ---- o2: bufB @ Wo2[64,256]^T + bo2 -> out (waves 0-3) ----
    if (w < 4) {
        const int n = w * 16 + l15;
        pB[0] = w * 4096;
        Chi[0] = float4_t{0,0,0,0}; Clo[0] = float4_t{0,0,0,0};
        aFrag = bufB + l15 * AST + g4 * 8;
        frag_gemm<1, 8>(aFrag, tail + O2H, tail + O2H + 16384, pB, lane8, Chi, Clo);
        const float b = bo2[n];
#pragma unroll
        for (int r = 0; r < 4; ++r)
            out[(r0 + g4 * 4 + r) * OUTD + n] = Chi[0][r] + Clo[0][r] * HL_INV + b;
    }
}

// ---------------------------------------------------------------------------
extern "C" void kernel_launch(void* const* d_in, const int* in_sizes, int n_in,
                              void* d_out, int out_size, void* d_ws, size_t ws_size,
                              hipStream_t stream) {
    const float* x      = (const float*)d_in[0];
    const float* hidden = (const float*)d_in[1];
    const float* h0     = (const float*)d_in[2];
    const float* c0     = (const float*)d_in[3];
    const float* Wf1    = (const float*)d_in[4];
    const float* bf1    = (const float*)d_in[5];
    const float* Wf2    = (const float*)d_in[6];
    const float* bf2    = (const float*)d_in[7];
    const float* Wf3    = (const float*)d_in[8];
    const float* bf3    = (const float*)d_in[9];
    const float* Wg1    = (const float*)d_in[10];
    const float* bg1    = (const float*)d_in[11];
    const float* Wg2    = (const float*)d_in[12];
    const float* bg2    = (const float*)d_in[13];
    const float* Wg3    = (const float*)d_in[14];
    const float* bg3    = (const float*)d_in[15];
    const float* W_ih   = (const float*)d_in[16];
    const float* W_hh   = (const float*)d_in[17];
    const float* b_ih   = (const float*)d_in[18];
    const float* b_hh   = (const float*)d_in[19];
    const float* Wo1    = (const float*)d_in[20];
    const float* bo1    = (const float*)d_in[21];
    const float* Wo2    = (const float*)d_in[22];
    const float* bo2    = (const float*)d_in[23];

    char* wsb = (char*)d_ws;
    float*  A32  = (float*)(wsb + 0);
    float*  B32  = (float*)(wsb + 524288);
    half_t* Whi  = (half_t*)(wsb + 1048576);
    half_t* Wlo  = (half_t*)(wsb + 1179648);
    float*  S    = (float*)(wsb + 1310720);
    half_t* tail = (half_t*)(wsb + WS_TAIL_B);

    float* outp  = (float*)d_out;              // [512,64]
    float* hid1  = (float*)d_out + 32768;      // hidden_new [512,128]
    float* hid2  = (float*)d_out + 98304;      // hidden_new[None]
    float* cout  = (float*)d_out + 163840;     // c_new[None]

    hipMemsetAsync(S, 0, (size_t)NN * F2D * sizeof(float), stream);

    k0_prep<<<dim3(368), dim3(256), 0, stream>>>(Wf3, Wg1, Wg2, Wg3,
                                                 W_ih, W_hh, Wo1, Wo2, tail);

    k1_proj<<<dim3(128), dim3(256), 0, stream>>>(hidden, Wf1, bf1, Wf2,
                                                 A32, B32, Whi, Wlo);

    k2_pairwise<<<dim3(8, 32), dim3(512), 0, stream>>>(A32, B32, Whi, Wlo, bf2, S);

    k4_tail<<<dim3(32), dim3(512), 0, stream>>>(S, x, h0, c0, tail,
                                                bf3, bg1, bg2, bg3,
                                                b_ih, b_hh, bo1, bo2,
                                                outp, hid1, hid2, cout);
}

// Round 7
// 213.620 us; speedup vs baseline: 1.5086x; 1.0475x over previous
//
#include <hip/hip_runtime.h>
#include <hip/hip_bf16.h>

// ---------------------------------------------------------------------------
// RRN forward, MI355X.
//   k0: unified prep — frag-pack ALL f16 hi/lo weights (Wf2 + 7 tail mats,
//       LDS-staged, coalesced both sides) + Wf1 64x64 tile transpose -> WT1.
//   k1: A32/B32 projections (fp32) via WT1 (coalesced weight reads).
//   k2: pairwise MLP, producer/consumer h staging; W fragments PINNED in
//       VGPRs via asm "+v" (anti-rematerialization), frag-packed loads.
//   k4: fused MFMA tail (round-5 verified).
//   FIX vs round 6: WT1 moved past the TRUE tail end (3342336) — the
//   previous 3309568 overlapped the O2 lo plane by 32KB (race -> inf -> NaN).
// ---------------------------------------------------------------------------

#define NN   512
#define HH   128
#define F1D  256
#define F2D  256
#define OUTD 64
#define ICHUNK 64

typedef _Float16 half_t;
typedef _Float16 half8 __attribute__((ext_vector_type(8)));
typedef float float4_t __attribute__((ext_vector_type(4)));
typedef float float8_t __attribute__((ext_vector_type(8)));

__device__ __forceinline__ float sigmoidf_(float x) {
    return 1.0f / (1.0f + __expf(-x));
}

#define HL_INV 2.44140625e-4f

// ---- workspace layout (bytes) ----
// A32 0 (512K) | B32 524288 (512K) | W2H 1048576 (128K) | W2L 1179648 (128K)
// S 1310720 (512K) | tail 1835008..3342336 (1.507M) | WT1 3342336 (256K)
#define WS_TAIL_B 1835008
#define WS_WT1_B  3342336
// f16-element offsets within tail region (hi base; lo = hi + cnt):
#define T3H 0
#define G1H 65536
#define G2H 196608
#define G3H 327680
#define CATH 393216
#define O1H 655360
#define O2H 720896

// ---------------- k0: unified weight prep ----------------
// blocks 0..115: frag-pack one 16-row panel of one matrix (hi/lo f16).
// blocks 116..131: Wf1 64x64 transpose tiles -> WT1[k][n].
// frag layout per [N][K] matrix: idx = (n>>4)*(16K) + (k>>5)*512
//                                     + ((k>>3)&3)*128 + (n&15)*8 + (k&7)
__constant__ int p_cum[8]   = {16, 24, 40, 56, 64, 96, 112, 116};
__constant__ int p_K[8]     = {256, 256, 256, 256, 256, 256, 128, 256};
__constant__ int p_hioff[8] = {0, T3H, G1H, G2H, G3H, CATH, O1H, O2H};
__constant__ int p_cnt[8]   = {65536, 32768, 65536, 65536, 32768, 131072, 32768, 16384};

__global__ __launch_bounds__(256)
void k0_prep(const float* __restrict__ Wf1,
             const float* __restrict__ Wf2,
             const float* __restrict__ Wf3,
             const float* __restrict__ Wg1, const float* __restrict__ Wg2,
             const float* __restrict__ Wg3,
             const float* __restrict__ W_ih, const float* __restrict__ W_hh,
             const float* __restrict__ Wo1, const float* __restrict__ Wo2,
             half_t* __restrict__ tail,
             half_t* __restrict__ W2H, half_t* __restrict__ W2L,
             float* __restrict__ WT1) {
    __shared__ float slab[4096];
    __shared__ float tile[64][65];
    const int t = threadIdx.x;
    const int bid = blockIdx.x;

    if (bid < 116) {
        int m = 0;
        while (m < 7 && bid >= p_cum[m]) ++m;
        const int pl = bid - (m ? p_cum[m - 1] : 0);
        const int K = p_K[m];
        const int kshift = (K == 256) ? 8 : 7;
        const int n0 = pl * 16;

        const float* src;
        switch (m) {
            case 0: src = Wf2; break;
            case 1: src = Wf3; break;
            case 2: src = Wg1; break;
            case 3: src = Wg2; break;
            case 4: src = Wg3; break;
            case 6: src = Wo1; break;
            default: src = Wo2; break;  // m==7 ; m==5 handled below
        }
        for (int q = t; q < (16 * K) / 4; q += 256) {
            const int flat = q * 4;
            const int r = flat >> kshift;
            const int k = flat & (K - 1);
            float4_t v;
            if (m == 5) {
                v = (k < 128) ? *(const float4_t*)(W_ih + (n0 + r) * 128 + k)
                              : *(const float4_t*)(W_hh + (n0 + r) * 128 + (k - 128));
            } else {
                v = *(const float4_t*)(src + (size_t)(n0 + r) * K + k);
            }
            *(float4_t*)&slab[flat] = v;
        }
        __syncthreads();

        half_t *hi, *lo;
        if (m == 0) { hi = W2H; lo = W2L; }
        else        { hi = tail + p_hioff[m]; lo = hi + p_cnt[m]; }
        const int base = pl * (K << 4);
        for (int f0 = t * 8; f0 < 16 * K; f0 += 2048) {
            const int ks = f0 >> 9;
            const int g4 = (f0 >> 7) & 3;
            const int l15 = (f0 >> 3) & 15;
            const int k0 = ks * 32 + g4 * 8;
            float8_t v = *(const float8_t*)&slab[l15 * K + k0];
            half8 hv, lv;
#pragma unroll
            for (int e = 0; e < 8; ++e) {
                half_t h = (half_t)v[e];
                hv[e] = h;
                lv[e] = (half_t)((v[e] - (float)h) * 4096.0f);
            }
            *(half8*)(hi + base + f0) = hv;
            *(half8*)(lo + base + f0) = lv;
        }
    } else {
        // Wf1 [256][256] transpose -> WT1[k][n]
        const int local = bid - 116;
        const int tr = local >> 2, tc = local & 3;
#pragma unroll
        for (int q = 0; q < 16; ++q) {
            const int idx = q * 256 + t;
            const int ly = idx >> 6, lx = idx & 63;
            tile[ly][lx] = Wf1[(tr * 64 + ly) * 256 + tc * 64 + lx];
        }
        __syncthreads();
#pragma unroll
        for (int q = 0; q < 16; ++q) {
            const int idx = q * 256 + t;
            const int ly = idx >> 6, lx = idx & 63;
            WT1[(tc * 64 + ly) * 256 + tr * 64 + lx] = tile[lx][ly];
        }
    }
}

// ---------------- k1: projections (fp32 out), coalesced via WT1 ----------------
// 128 blocks x 256 threads, 4 rows each; thread t owns neuron n=t.
__global__ __launch_bounds__(256)
void k1_proj(const float* __restrict__ hidden,
             const float* __restrict__ WT1,
             const float* __restrict__ bf1,
             float* __restrict__ A32,
             float* __restrict__ B32) {
    __shared__ float hid[4][HH];
    const int t = threadIdx.x;
    const int i0 = blockIdx.x * 4;
    for (int q = t; q < 4 * HH; q += 256)
        hid[q >> 7][q & 127] = hidden[(i0 + (q >> 7)) * HH + (q & 127)];
    __syncthreads();

    float accA[4], accB[4];
    const float b = bf1[t];
#pragma unroll
    for (int r = 0; r < 4; ++r) { accA[r] = b; accB[r] = 0.0f; }

    const float* wcol = WT1 + t;
#pragma unroll 4
    for (int kk = 0; kk < HH; ++kk) {
        const float va = wcol[kk * 256];
        const float vb = wcol[(kk + 128) * 256];
#pragma unroll
        for (int r = 0; r < 4; ++r) {
            const float h = hid[r][kk];
            accA[r] = fmaf(h, va, accA[r]);
            accB[r] = fmaf(h, vb, accB[r]);
        }
    }
#pragma unroll
    for (int r = 0; r < 4; ++r) {
        A32[(i0 + r) * F1D + t] = accA[r];
        B32[(i0 + r) * F1D + t] = accB[r];
    }
}

// ---------------- k2: pairwise MLP, W pinned in VGPRs ----------------
// grid (8 i-chunks, 32 j-tiles) x 512 threads (8 waves), 1 block/CU.
// wave w: produces h fragment for k-slice ks=w; consumes all 8 for its
// n-range [w*32, w*32+32). hbuf double-buffered, 1 barrier/iter.
__global__ __launch_bounds__(512, 2)
void k2_pairwise(const float* __restrict__ A32,
                 const float* __restrict__ B32,
                 const half_t* __restrict__ W2H,
                 const half_t* __restrict__ W2L,
                 const float* __restrict__ bf2,
                 float* __restrict__ S) {
    __shared__ half_t hbuf[2][8][512];   // [dbuf][ks][lane*8] = 2 x 8KB

    const int tid = threadIdx.x;
    const int lane = tid & 63;
    const int w = tid >> 6;           // wave 0..7
    const int l15 = lane & 15;
    const int g4 = lane >> 4;         // 0..3
    const int j0 = blockIdx.y * 16;
    const int i0 = blockIdx.x * ICHUNK;

    // W fragments, frag-packed (coalesced): half8 idx = (w*2+nt)*512 + ks*64 + lane
    const half8* WH8 = (const half8*)W2H;
    const half8* WL8 = (const half8*)W2L;
    half8 Wh[2][8], Wl[2][8];
#pragma unroll
    for (int nt = 0; nt < 2; ++nt)
#pragma unroll
        for (int ks = 0; ks < 8; ++ks) {
            const int idx = (w * 2 + nt) * 512 + ks * 64 + lane;
            Wh[nt][ks] = WH8[idx];
            Wl[nt][ks] = WL8[idx];
        }
    // PIN: opaque def -> compiler cannot rematerialize the loads inside the loop
#pragma unroll
    for (int nt = 0; nt < 2; ++nt)
#pragma unroll
        for (int ks = 0; ks < 8; ++ks) {
            asm volatile("" : "+v"(Wh[nt][ks]));
            asm volatile("" : "+v"(Wl[nt][ks]));
        }

    // producer's B slice: B[j=l15][k = w*32 + g4*8 .. +8]
    float4_t Bw0 = *(const float4_t*)(B32 + (size_t)(j0 + l15) * F1D + w * 32 + g4 * 8);
    float4_t Bw1 = *(const float4_t*)(B32 + (size_t)(j0 + l15) * F1D + w * 32 + g4 * 8 + 4);
    asm volatile("" : "+v"(Bw0));
    asm volatile("" : "+v"(Bw1));

    float b2v[2];
#pragma unroll
    for (int nt = 0; nt < 2; ++nt) b2v[nt] = bf2[w * 32 + nt * 16 + l15];

    float4_t acc[2];
#pragma unroll
    for (int nt = 0; nt < 2; ++nt)
#pragma unroll
        for (int r = 0; r < 4; ++r) acc[nt][r] = 0.0f;

    // prologue: produce h(0)
    {
        const float* Ap = A32 + (size_t)i0 * F1D + w * 32 + g4 * 8;
        float4_t a0 = *(const float4_t*)Ap;
        float4_t a1 = *(const float4_t*)(Ap + 4);
        half8 hf;
#pragma unroll
        for (int e = 0; e < 4; ++e) {
            hf[e]     = (half_t)fmaxf(a0[e] + Bw0[e], 0.0f);
            hf[4 + e] = (half_t)fmaxf(a1[e] + Bw1[e], 0.0f);
        }
        *(half8*)&hbuf[0][w][lane * 8] = hf;
    }
    __syncthreads();

    int p = 0;
    for (int io = 0; io < ICHUNK; ++io) {
        // prefetch next A slice early (hides L2 latency under MFMA)
        float4_t a0, a1;
        if (io + 1 < ICHUNK) {
            const float* Ap = A32 + (size_t)(i0 + io + 1) * F1D + w * 32 + g4 * 8;
            a0 = *(const float4_t*)Ap;
            a1 = *(const float4_t*)(Ap + 4);
        }

        // MFMA phase on hbuf[p]
        float4_t C[2], Cl[2];
#pragma unroll
        for (int nt = 0; nt < 2; ++nt)
#pragma unroll
            for (int r = 0; r < 4; ++r) { C[nt][r] = 0.0f; Cl[nt][r] = 0.0f; }

#pragma unroll
        for (int ks = 0; ks < 8; ++ks) {
            half8 hf = *(const half8*)&hbuf[p][ks][lane * 8];
            C[0]  = __builtin_amdgcn_mfma_f32_16x16x32_f16(hf, Wh[0][ks], C[0], 0, 0, 0);
            C[1]  = __builtin_amdgcn_mfma_f32_16x16x32_f16(hf, Wh[1][ks], C[1], 0, 0, 0);
            Cl[0] = __builtin_amdgcn_mfma_f32_16x16x32_f16(hf, Wl[0][ks], Cl[0], 0, 0, 0);
            Cl[1] = __builtin_amdgcn_mfma_f32_16x16x32_f16(hf, Wl[1][ks], Cl[1], 0, 0, 0);
        }

        // produce h(io+1) into hbuf[p^1]
        if (io + 1 < ICHUNK) {
            half8 hf;
#pragma unroll
            for (int e = 0; e < 4; ++e) {
                hf[e]     = (half_t)fmaxf(a0[e] + Bw0[e], 0.0f);
                hf[4 + e] = (half_t)fmaxf(a1[e] + Bw1[e], 0.0f);
            }
            *(half8*)&hbuf[p ^ 1][w][lane * 8] = hf;
        }

        // epilogue: h2 = relu(C + Cl/4096 + bf2), accumulate over i
#pragma unroll
        for (int nt = 0; nt < 2; ++nt) {
#pragma unroll
            for (int r = 0; r < 4; ++r) {
                float v = fmaf(Cl[nt][r], HL_INV, C[nt][r]) + b2v[nt];
                acc[nt][r] += fmaxf(v, 0.0f);
            }
        }
        __syncthreads();
        p ^= 1;
    }

    // C layout: col = l15 (n), row = g4*4 + r (jj)
#pragma unroll
    for (int nt = 0; nt < 2; ++nt)
#pragma unroll
        for (int r = 0; r < 4; ++r)
            atomicAdd(&S[(size_t)(j0 + g4 * 4 + r) * F2D + w * 32 + nt * 16 + l15], acc[nt][r]);
}

// ---------------- k4: fused MFMA tail (round-5 verified) ----------------
#define AST 260   // LDS activation row stride (floats)

template<int NT, int NKS>
__device__ __forceinline__ void frag_gemm(const float* __restrict__ aPtr,
                                          const half_t* __restrict__ WhF,
                                          const half_t* __restrict__ WlF,
                                          const int* pB, int lane8,
                                          float4_t* Chi, float4_t* Clo) {
#pragma unroll
    for (int ks = 0; ks < NKS; ++ks) {
        float4_t a0 = *(const float4_t*)(aPtr + ks * 32);
        float4_t a1 = *(const float4_t*)(aPtr + ks * 32 + 4);
        half8 ah, al;
#pragma unroll
        for (int e = 0; e < 4; ++e) {
            half_t h0 = (half_t)a0[e];
            ah[e] = h0; al[e] = (half_t)((a0[e] - (float)h0) * 4096.0f);
            half_t h1 = (half_t)a1[e];
            ah[4+e] = h1; al[4+e] = (half_t)((a1[e] - (float)h1) * 4096.0f);
        }
#pragma unroll
        for (int nt = 0; nt < NT; ++nt) {
            half8 wh = *(const half8*)(WhF + pB[nt] + ks * 512 + lane8);
            half8 wl = *(const half8*)(WlF + pB[nt] + ks * 512 + lane8);
            Chi[nt] = __builtin_amdgcn_mfma_f32_16x16x32_f16(ah, wh, Chi[nt], 0, 0, 0);
            Clo[nt] = __builtin_amdgcn_mfma_f32_16x16x32_f16(ah, wl, Clo[nt], 0, 0, 0);
            Clo[nt] = __builtin_amdgcn_mfma_f32_16x16x32_f16(al, wh, Clo[nt], 0, 0, 0);
        }
    }
}

__global__ __launch_bounds__(512)
void k4_tail(const float* __restrict__ S,
             const float* __restrict__ x,
             const float* __restrict__ h0,
             const float* __restrict__ c0,
             const half_t* __restrict__ tail,
             const float* __restrict__ bf3,
             const float* __restrict__ bg1, const float* __restrict__ bg2,
             const float* __restrict__ bg3,
             const float* __restrict__ b_ih, const float* __restrict__ b_hh,
             const float* __restrict__ bo1, const float* __restrict__ bo2,
             float* __restrict__ out,
             float* __restrict__ hid_out,
             float* __restrict__ h_out,
             float* __restrict__ c_out) {
    __shared__ float bufA[16 * AST];
    __shared__ float bufB[16 * AST];
    __shared__ float bufC[16 * AST];
    const int tid = threadIdx.x;
    const int lane = tid & 63;
    const int w = tid >> 6;
    const int l15 = lane & 15;
    const int g4 = lane >> 4;
    const int r0 = blockIdx.x * 16;
    const int lane8 = lane * 8;

    for (int q = tid; q < 16 * 256; q += 512)
        bufC[(q >> 8) * AST + (q & 255)] = S[(size_t)(r0 + (q >> 8)) * 256 + (q & 255)];
    for (int q = tid; q < 16 * 128; q += 512)
        bufA[(q >> 7) * AST + (q & 127)] = x[(r0 + (q >> 7)) * 128 + (q & 127)];
    __syncthreads();

    const float* aFrag;
    int pB[4];
    float4_t Chi[4], Clo[4];

    // ---- SM ----
    {
        const int n = w * 16 + l15;
        pB[0] = w * 4096;
        Chi[0] = float4_t{0,0,0,0}; Clo[0] = float4_t{0,0,0,0};
        aFrag = bufC + l15 * AST + g4 * 8;
        frag_gemm<1, 8>(aFrag, tail + T3H, tail + T3H + 32768, pB, lane8, Chi, Clo);
        const float b = 512.0f * bf3[n];
#pragma unroll
        for (int r = 0; r < 4; ++r)
            bufA[(g4 * 4 + r) * AST + 128 + n] = Chi[0][r] + Clo[0][r] * HL_INV + b;
    }
    __syncthreads();

    // ---- g1 ----
    {
        pB[0] = (w * 2) * 4096; pB[1] = (w * 2 + 1) * 4096;
        Chi[0] = float4_t{0,0,0,0}; Clo[0] = float4_t{0,0,0,0};
        Chi[1] = float4_t{0,0,0,0}; Clo[1] = float4_t{0,0,0,0};
        aFrag = bufA + l15 * AST + g4 * 8;
        frag_gemm<2, 8>(aFrag, tail + G1H, tail + G1H + 65536, pB, lane8, Chi, Clo);
#pragma unroll
        for (int nt = 0; nt < 2; ++nt) {
            const int n = w * 32 + nt * 16 + l15;
            const float b = bg1[n];
#pragma unroll
            for (int r = 0; r < 4; ++r)
                bufB[(g4 * 4 + r) * AST + n] = fmaxf(Chi[nt][r] + Clo[nt][r] * HL_INV + b, 0.0f);
        }
    }
    __syncthreads();

    // ---- g2 (+ stage h0) ----
    {
        pB[0] = (w * 2) * 4096; pB[1] = (w * 2 + 1) * 4096;
        Chi[0] = float4_t{0,0,0,0}; Clo[0] = float4_t{0,0,0,0};
        Chi[1] = float4_t{0,0,0,0}; Clo[1] = float4_t{0,0,0,0};
        aFrag = bufB + l15 * AST + g4 * 8;
        frag_gemm<2, 8>(aFrag, tail + G2H, tail + G2H + 65536, pB, lane8, Chi, Clo);
#pragma unroll
        for (int nt = 0; nt < 2; ++nt) {
            const int n = w * 32 + nt * 16 + l15;
            const float b = bg2[n];
#pragma unroll
            for (int r = 0; r < 4; ++r)
                bufC[(g4 * 4 + r) * AST + n] = fmaxf(Chi[nt][r] + Clo[nt][r] * HL_INV + b, 0.0f);
        }
        for (int q = tid; q < 16 * 128; q += 512)
            bufA[(q >> 7) * AST + 128 + (q & 127)] = h0[(r0 + (q >> 7)) * 128 + (q & 127)];
    }
    __syncthreads();

    // ---- g3 ----
    {
        const int n = w * 16 + l15;
        pB[0] = w * 4096;
        Chi[0] = float4_t{0,0,0,0}; Clo[0] = float4_t{0,0,0,0};
        aFrag = bufC + l15 * AST + g4 * 8;
        frag_gemm<1, 8>(aFrag, tail + G3H, tail + G3H + 32768, pB, lane8, Chi, Clo);
        const float b = bg3[n];
#pragma unroll
        for (int r = 0; r < 4; ++r)
            bufA[(g4 * 4 + r) * AST + n] = Chi[0][r] + Clo[0][r] * HL_INV + b;
    }
    __syncthreads();

    // ---- gates + LSTM in-register ----
    {
#pragma unroll
        for (int nt = 0; nt < 4; ++nt) {
            pB[nt] = (w + nt * 8) * 4096;
            Chi[nt] = float4_t{0,0,0,0}; Clo[nt] = float4_t{0,0,0,0};
        }
        aFrag = bufA + l15 * AST + g4 * 8;
        frag_gemm<4, 8>(aFrag, tail + CATH, tail + CATH + 131072, pB, lane8, Chi, Clo);

        const int nh = w * 16 + l15;
        float bi = b_ih[nh]       + b_hh[nh];
        float bf = b_ih[128 + nh] + b_hh[128 + nh];
        float bg = b_ih[256 + nh] + b_hh[256 + nh];
        float bo = b_ih[384 + nh] + b_hh[384 + nh];
#pragma unroll
        for (int r = 0; r < 4; ++r) {
            const int row = r0 + g4 * 4 + r;
            float gi = sigmoidf_(Chi[0][r] + Clo[0][r] * HL_INV + bi);
            float gf = sigmoidf_(Chi[1][r] + Clo[1][r] * HL_INV + bf);
            float gg = tanhf(    Chi[2][r] + Clo[2][r] * HL_INV + bg);
            float go = sigmoidf_(Chi[3][r] + Clo[3][r] * HL_INV + bo);
            float c = gf * c0[row * 128 + nh] + gi * gg;
            float h = go * tanhf(c);
            bufC[(g4 * 4 + r) * AST + nh] = h;
            hid_out[row * 128 + nh] = h;
            h_out[row * 128 + nh]   = h;
            c_out[row * 128 + nh]   = c;
        }
    }
    __syncthreads();

    // ---- o1 ----
    {
        pB[0] = (w * 2) * 2048; pB[1] = (w * 2 + 1) * 2048;
        Chi[0] = float4_t{0,0,0,0}; Clo[0] = float4_t{0,0,0,0};
        Chi[1] = float4_t{0,0,0,0}; Clo[1] = float4_t{0,0,0,0};
        aFrag = bufC + l15 * AST + g4 * 8;
        frag_gemm<2, 4>(aFrag, tail + O1H, tail + O1H + 32768, pB, lane8, Chi, Clo);
#pragma unroll
        for (int nt = 0; nt < 2; ++nt) {
            const int n = w * 32 + nt * 16 + l15;
            const float b = bo1[n];
#pragma unroll
            for (int r = 0; r < 4; ++r)
                bufB[(g4 * 4 + r) * AST + n] = fmaxf(Chi[nt][r] + Clo[nt][r] * HL_INV + b, 0.0f);
        }
    }
    __syncthreads();

    // ---- o2 ----
    if (w < 4) {
        const int n = w * 16 + l15;
        pB[0] = w * 4096;
        Chi[0] = float4_t{0,0,0,0}; Clo[0] = float4_t{0,0,0,0};
        aFrag = bufB + l15 * AST + g4 * 8;
        frag_gemm<1, 8>(aFrag, tail + O2H, tail + O2H + 16384, pB, lane8, Chi, Clo);
        const float b = bo2[n];
#pragma unroll
        for (int r = 0; r < 4; ++r)
            out[(r0 + g4 * 4 + r) * OUTD + n] = Chi[0][r] + Clo[0][r] * HL_INV + b;
    }
}

// ---------------------------------------------------------------------------
extern "C" void kernel_launch(void* const* d_in, const int* in_sizes, int n_in,
                              void* d_out, int out_size, void* d_ws, size_t ws_size,
                              hipStream_t stream) {
    const float* x      = (const float*)d_in[0];
    const float* hidden = (const float*)d_in[1];
    const float* h0     = (const float*)d_in[2];
    const float* c0     = (const float*)d_in[3];
    const float* Wf1    = (const float*)d_in[4];
    const float* bf1    = (const float*)d_in[5];
    const float* Wf2    = (const float*)d_in[6];
    const float* bf2    = (const float*)d_in[7];
    const float* Wf3    = (const float*)d_in[8];
    const float* bf3    = (const float*)d_in[9];
    const float* Wg1    = (const float*)d_in[10];
    const float* bg1    = (const float*)d_in[11];
    const float* Wg2    = (const float*)d_in[12];
    const float* bg2    = (const float*)d_in[13];
    const float* Wg3    = (const float*)d_in[14];
    const float* bg3    = (const float*)d_in[15];
    const float* W_ih   = (const float*)d_in[16];
    const float* W_hh   = (const float*)d_in[17];
    const float* b_ih   = (const float*)d_in[18];
    const float* b_hh   = (const float*)d_in[19];
    const float* Wo1    = (const float*)d_in[20];
    const float* bo1    = (const float*)d_in[21];
    const float* Wo2    = (const float*)d_in[22];
    const float* bo2    = (const float*)d_in[23];

    char* wsb = (char*)d_ws;
    float*  A32  = (float*)(wsb + 0);
    float*  B32  = (float*)(wsb + 524288);
    half_t* W2H  = (half_t*)(wsb + 1048576);
    half_t* W2L  = (half_t*)(wsb + 1179648);
    float*  S    = (float*)(wsb + 1310720);
    half_t* tail = (half_t*)(wsb + WS_TAIL_B);
    float*  WT1  = (float*)(wsb + WS_WT1_B);

    float* outp  = (float*)d_out;              // [512,64]
    float* hid1  = (float*)d_out + 32768;      // hidden_new [512,128]
    float* hid2  = (float*)d_out + 98304;      // hidden_new[None]
    float* cout  = (float*)d_out + 163840;     // c_new[None]

    hipMemsetAsync(S, 0, (size_t)NN * F2D * sizeof(float), stream);

    k0_prep<<<dim3(132), dim3(256), 0, stream>>>(Wf1, Wf2, Wf3, Wg1, Wg2, Wg3,
                                                 W_ih, W_hh, Wo1, Wo2,
                                                 tail, W2H, W2L, WT1);

    k1_proj<<<dim3(128), dim3(256), 0, stream>>>(hidden, WT1, bf1, A32, B32);

    k2_pairwise<<<dim3(8, 32), dim3(512), 0, stream>>>(A32, B32, W2H, W2L, bf2, S);

    k4_tail<<<dim3(32), dim3(512), 0, stream>>>(S, x, h0, c0, tail,
                                                bf3, bg1, bg2, bg3,
                                                b_ih, b_hh, bo1, bo2,
                                                outp, hid1, hid2, cout);
}